// Round 4
// baseline (258.165 us; speedup 1.0000x reference)
//
#include <hip/hip_runtime.h>
#include <math.h>

// Problem constants (setup_inputs is fixed: P=4, A=4096)
#define A_ATOMS 4096
#define P_POSES 4
#define N_TOT   (A_ATOMS * P_POSES)
#define TILE    128
#define NTILES  (A_ATOMS / TILE)             // 32
#define NPAIRT  (NTILES * (NTILES + 1) / 2)  // 528 upper-tri tiles per pose
#define NTAU    (NPAIRT * P_POSES)           // 2112 total tiles

#define GRID_B  512                          // <= guaranteed co-resident (needs only 2 blocks/CU)
#define NWORK   (GRID_B - P_POSES)           // 508 LJ worker blocks
#define FK_T    256
#define FK_CH   (A_ATOMS / FK_T)             // 16 atoms per FK thread
#define FLAG_MAGIC 0x13572468u               // != 0xAAAAAAAA ws poison

typedef float v2f __attribute__((ext_vector_type(2)));

__device__ __constant__ float c_SIGMA2  = 1.9f * 1.9f;
__device__ __constant__ float c_4EPS    = 0.8f;   // 4 * 0.2
__device__ __constant__ float c_R2SOFT  = 0.25f;

// ---------------- rigid transform (3x4 row-major: r|t) ----------------
struct RT { float m[12]; };

__device__ inline RT rt_identity() {
    RT v;
    v.m[0]=1.f; v.m[1]=0.f; v.m[2]=0.f;  v.m[3]=0.f;
    v.m[4]=0.f; v.m[5]=1.f; v.m[6]=0.f;  v.m[7]=0.f;
    v.m[8]=0.f; v.m[9]=0.f; v.m[10]=1.f; v.m[11]=0.f;
    return v;
}

// C = A o B  (left-to-right chain product: cum = cum @ ht)
__device__ inline RT rt_compose(const RT& a, const RT& b) {
    RT c;
#pragma unroll
    for (int i = 0; i < 3; ++i) {
        float a0 = a.m[i*4+0], a1 = a.m[i*4+1], a2 = a.m[i*4+2];
        c.m[i*4+0] = fmaf(a0, b.m[0], fmaf(a1, b.m[4],  a2*b.m[8]));
        c.m[i*4+1] = fmaf(a0, b.m[1], fmaf(a1, b.m[5],  a2*b.m[9]));
        c.m[i*4+2] = fmaf(a0, b.m[2], fmaf(a1, b.m[6],  a2*b.m[10]));
        c.m[i*4+3] = fmaf(a0, b.m[3], fmaf(a1, b.m[7],  fmaf(a2, b.m[11], a.m[i*4+3])));
    }
    return c;
}

// Accurate trig kept on purpose: the 4096-long compose chain amplifies per-HT
// error; don't trade correctness margin for ~1 us.
__device__ inline RT local_ht(const float* __restrict__ dof) {
    float phi = dof[0], th = dof[1];
    float d = fmaf(0.25f, tanhf(dof[2]), 1.5f);
    float sp, cp, st, ct;
    sincosf(phi, &sp, &cp);
    sincosf(th,  &st, &ct);
    RT h;
    h.m[0] = cp*ct; h.m[1] = -sp; h.m[2]  = cp*st; h.m[3]  = d*cp*ct;
    h.m[4] = sp*ct; h.m[5] =  cp; h.m[6]  = sp*st; h.m[7]  = d*sp*ct;
    h.m[8] = -st;   h.m[9] = 0.f; h.m[10] = ct;    h.m[11] = -d*st;
    return h;
}

// ---------------- single fused persistent kernel ----------------
// blocks 0..3: forward kinematics for pose = blockIdx.x, then release flag[pose]
// blocks 4..511: acquire-wait on all flags, then sweep LJ tiles (stride NWORK)
__global__ __launch_bounds__(256, 2)
void fused_kernel(const float* __restrict__ dofs,
                  const int*   __restrict__ kid,
                  float*       __restrict__ out,
                  float*       __restrict__ X,
                  float*       __restrict__ Y,
                  float*       __restrict__ Z,
                  float4*      __restrict__ hp0,
                  float4*      __restrict__ hp1,
                  float4*      __restrict__ hp2,
                  unsigned*    __restrict__ flags) {
    __shared__ __align__(16) float smem[2 * 3 * FK_T * 4];   // 24 KB (FK scan); LJ reuses front
    const int tid = threadIdx.x;

    if (blockIdx.x < P_POSES) {
        // ======================= FK =======================
        const int pose = blockIdx.x;
        const int a0 = tid * FK_CH;
        const float* dbase = dofs + (size_t)pose * A_ATOMS * 9;

        float4* s0 = (float4*)smem;      // [2][FK_T]
        float4* s1 = s0 + 2 * FK_T;
        float4* s2 = s1 + 2 * FK_T;

        // phase 1: chunk product; spill local HTs to ws scratch (coalesced float4 planes)
        RT M;
#pragma unroll
        for (int k = 0; k < FK_CH; ++k) {
            RT h = local_ht(dbase + (size_t)(a0 + k) * 9);
            size_t si = ((size_t)pose * FK_CH + k) * FK_T + tid;
            hp0[si] = make_float4(h.m[0], h.m[1], h.m[2],  h.m[3]);
            hp1[si] = make_float4(h.m[4], h.m[5], h.m[6],  h.m[7]);
            hp2[si] = make_float4(h.m[8], h.m[9], h.m[10], h.m[11]);
            if (k == 0) M = h; else M = rt_compose(M, h);
        }

        int cur = 0;
        s0[cur * FK_T + tid] = make_float4(M.m[0], M.m[1], M.m[2],  M.m[3]);
        s1[cur * FK_T + tid] = make_float4(M.m[4], M.m[5], M.m[6],  M.m[7]);
        s2[cur * FK_T + tid] = make_float4(M.m[8], M.m[9], M.m[10], M.m[11]);
        __syncthreads();

        // inclusive Hillis-Steele scan over 256 chunk products, ping-pong
        for (int off = 1; off < FK_T; off <<= 1) {
            float4 v0 = s0[cur * FK_T + tid];
            float4 v1 = s1[cur * FK_T + tid];
            float4 v2 = s2[cur * FK_T + tid];
            int nxt = 1 - cur;
            if (tid >= off) {
                RT v, l;
                v.m[0]=v0.x; v.m[1]=v0.y; v.m[2]=v0.z;  v.m[3]=v0.w;
                v.m[4]=v1.x; v.m[5]=v1.y; v.m[6]=v1.z;  v.m[7]=v1.w;
                v.m[8]=v2.x; v.m[9]=v2.y; v.m[10]=v2.z; v.m[11]=v2.w;
                float4 l0 = s0[cur * FK_T + tid - off];
                float4 l1 = s1[cur * FK_T + tid - off];
                float4 l2 = s2[cur * FK_T + tid - off];
                l.m[0]=l0.x; l.m[1]=l0.y; l.m[2]=l0.z;  l.m[3]=l0.w;
                l.m[4]=l1.x; l.m[5]=l1.y; l.m[6]=l1.z;  l.m[7]=l1.w;
                l.m[8]=l2.x; l.m[9]=l2.y; l.m[10]=l2.z; l.m[11]=l2.w;
                RT w = rt_compose(l, v);
                s0[nxt * FK_T + tid] = make_float4(w.m[0], w.m[1], w.m[2],  w.m[3]);
                s1[nxt * FK_T + tid] = make_float4(w.m[4], w.m[5], w.m[6],  w.m[7]);
                s2[nxt * FK_T + tid] = make_float4(w.m[8], w.m[9], w.m[10], w.m[11]);
            } else {
                s0[nxt * FK_T + tid] = v0;
                s1[nxt * FK_T + tid] = v1;
                s2[nxt * FK_T + tid] = v2;
            }
            __syncthreads();
            cur = nxt;
        }

        // exclusive prefix, replay chunk from ws scratch, scatter coords
        RT cm;
        if (tid == 0) cm = rt_identity();
        else {
            float4 p0 = s0[cur * FK_T + tid - 1];
            float4 p1 = s1[cur * FK_T + tid - 1];
            float4 p2 = s2[cur * FK_T + tid - 1];
            cm.m[0]=p0.x; cm.m[1]=p0.y; cm.m[2]=p0.z;  cm.m[3]=p0.w;
            cm.m[4]=p1.x; cm.m[5]=p1.y; cm.m[6]=p1.z;  cm.m[7]=p1.w;
            cm.m[8]=p2.x; cm.m[9]=p2.y; cm.m[10]=p2.z; cm.m[11]=p2.w;
        }
#pragma unroll
        for (int k = 0; k < FK_CH; ++k) {
            size_t si = ((size_t)pose * FK_CH + k) * FK_T + tid;
            float4 h0 = hp0[si], h1 = hp1[si], h2 = hp2[si];
            RT h;
            h.m[0]=h0.x; h.m[1]=h0.y; h.m[2]=h0.z;  h.m[3]=h0.w;
            h.m[4]=h1.x; h.m[5]=h1.y; h.m[6]=h1.z;  h.m[7]=h1.w;
            h.m[8]=h2.x; h.m[9]=h2.y; h.m[10]=h2.z; h.m[11]=h2.w;
            cm = rt_compose(cm, h);
            int g   = pose * A_ATOMS + a0 + k;
            int dst = kid[g];
            X[dst] = cm.m[3];
            Y[dst] = cm.m[7];
            Z[dst] = cm.m[11];
        }
        __syncthreads();   // all lanes' stores issued+drained before release
        if (tid == 0) {
            out[pose] = 0.f;
            __hip_atomic_store(&flags[pose], FLAG_MAGIC,
                               __ATOMIC_RELEASE, __HIP_MEMORY_SCOPE_AGENT);
        }
        return;
    }

    // ======================= LJ workers =======================
    if (tid == 0) {
        for (int p = 0; p < P_POSES; ++p) {
            int guard = 0;
            while (__hip_atomic_load(&flags[p], __ATOMIC_ACQUIRE,
                                     __HIP_MEMORY_SCOPE_AGENT) != FLAG_MAGIC) {
                __builtin_amdgcn_s_sleep(2);
                if (++guard > (1 << 24)) break;   // fail loud (wrong), never hang
            }
        }
    }
    __syncthreads();

    float* sxi = smem;
    float* syi = smem + 128;
    float* szi = smem + 256;
    float* sxj = smem + 384;
    float* syj = smem + 512;
    float* szj = smem + 640;
    float* wsum = smem + 768;

    const float SIG2 = c_SIGMA2, SOFT = c_R2SOFT;

    for (int tau = (int)blockIdx.x - P_POSES; tau < NTAU; tau += NWORK) {
        int pose = tau / NPAIRT;
        int rr   = tau - pose * NPAIRT;
        int bi = 0;
        while (rr >= NTILES - bi) { rr -= NTILES - bi; ++bi; }
        int bj = bi + rr;

        const float* Xp = X + pose * A_ATOMS;
        const float* Yp = Y + pose * A_ATOMS;
        const float* Zp = Z + pose * A_ATOMS;

        if (tid < TILE) {
            int gi = bi * TILE + tid;
            sxi[tid] = Xp[gi]; syi[tid] = Yp[gi]; szi[tid] = Zp[gi];
        } else {
            int t = tid - TILE;
            int gj = bj * TILE + t;
            sxj[t] = Xp[gj]; syj[t] = Yp[gj]; szj[t] = Zp[gj];
        }
        __syncthreads();

        const int i0 = (tid & 15) * 8;
        const int j0 = (tid >> 4) * 8;
        float acc = 0.f;

        if (bi != bj) {
            // off-diagonal tile (496/528 per pose): packed fp32 pairs
            float xi[8], yi[8], zi[8];
#pragma unroll
            for (int k = 0; k < 8; ++k) {
                xi[k] = sxi[i0 + k]; yi[k] = syi[i0 + k]; zi[k] = szi[i0 + k];
            }
            v2f xj2[4], yj2[4], zj2[4];
#pragma unroll
            for (int p = 0; p < 4; ++p) {
                xj2[p] = (v2f){sxj[j0 + 2*p], sxj[j0 + 2*p + 1]};
                yj2[p] = (v2f){syj[j0 + 2*p], syj[j0 + 2*p + 1]};
                zj2[p] = (v2f){szj[j0 + 2*p], szj[j0 + 2*p + 1]};
            }
            const v2f soft2 = (v2f){SOFT, SOFT};
            v2f acc2 = (v2f){0.f, 0.f};
#pragma unroll
            for (int p = 0; p < 4; ++p) {
#pragma unroll
                for (int k = 0; k < 8; ++k) {
                    v2f dx = xi[k] - xj2[p];
                    v2f dy = yi[k] - yj2[p];
                    v2f dz = zi[k] - zj2[p];
                    v2f r2 = __builtin_elementwise_fma(dx, dx,
                             __builtin_elementwise_fma(dy, dy,
                             __builtin_elementwise_fma(dz, dz, soft2)));
                    v2f rc = (v2f){__builtin_amdgcn_rcpf(r2.x), __builtin_amdgcn_rcpf(r2.y)};
                    v2f t  = SIG2 * rc;
                    v2f i6 = t * t * t;
                    acc2 += __builtin_elementwise_fma(i6, i6, -i6);   // inv12 - inv6
                }
            }
            acc = acc2.x + acc2.y;
        } else {
            // diagonal tile: keep only i < j
            float xi[8], yi[8], zi[8], xj[8], yj[8], zj[8];
#pragma unroll
            for (int k = 0; k < 8; ++k) {
                xi[k] = sxi[i0 + k]; yi[k] = syi[i0 + k]; zi[k] = szi[i0 + k];
                xj[k] = sxj[j0 + k]; yj[k] = syj[j0 + k]; zj[k] = szj[j0 + k];
            }
#pragma unroll
            for (int jj = 0; jj < 8; ++jj) {
                int j = j0 + jj;
#pragma unroll
                for (int k = 0; k < 8; ++k) {
                    float dx = xi[k] - xj[jj], dy = yi[k] - yj[jj], dz = zi[k] - zj[jj];
                    float r2 = fmaf(dx, dx, fmaf(dy, dy, fmaf(dz, dz, SOFT)));
                    float t  = SIG2 * __builtin_amdgcn_rcpf(r2);
                    float i6 = t * t * t;
                    float hh = fmaf(i6, i6, -i6);
                    acc += ((i0 + k) < j) ? hh : 0.f;
                }
            }
        }
        acc *= c_4EPS;

        // wave64 reduce then cross-wave via LDS
#pragma unroll
        for (int off = 32; off > 0; off >>= 1) acc += __shfl_down(acc, off, 64);
        int lane = tid & 63, wid = tid >> 6;
        if (lane == 0) wsum[wid] = acc;
        __syncthreads();
        if (tid == 0)
            atomicAdd(out + pose, wsum[0] + wsum[1] + wsum[2] + wsum[3]);
        // next iteration's staging is safe: tile-array reads all precede the
        // wsum __syncthreads above; wsum (offset 768) doesn't overlap tiles.
    }
}

// ---------------- launch ----------------
extern "C" void kernel_launch(void* const* d_in, const int* in_sizes, int n_in,
                              void* d_out, int out_size, void* d_ws, size_t ws_size,
                              hipStream_t stream) {
    (void)in_sizes; (void)n_in; (void)out_size; (void)ws_size;
    const float* dofs = (const float*)d_in[0];
    const int*   kid  = (const int*)d_in[2];
    float*       out  = (float*)d_out;

    float* X = (float*)d_ws;                     // N_TOT floats
    float* Y = X + N_TOT;
    float* Z = Y + N_TOT;
    float4* hp0 = (float4*)(Z + N_TOT);          // 3 planes x 16384 float4
    float4* hp1 = hp0 + (size_t)P_POSES * FK_CH * FK_T;
    float4* hp2 = hp1 + (size_t)P_POSES * FK_CH * FK_T;
    unsigned* flags = (unsigned*)(hp2 + (size_t)P_POSES * FK_CH * FK_T);

    fused_kernel<<<GRID_B, 256, 0, stream>>>(dofs, kid, out, X, Y, Z,
                                             hp0, hp1, hp2, flags);
}

// Round 5
// 100.611 us; speedup vs baseline: 2.5660x; 2.5660x over previous
//
#include <hip/hip_runtime.h>
#include <math.h>

// Problem constants (setup_inputs is fixed: P=4, A=4096)
#define A_ATOMS 4096
#define P_POSES 4
#define N_TOT   (A_ATOMS * P_POSES)
#define TILE    128
#define NTILES  (A_ATOMS / TILE)             // 32
#define NPAIRT  (NTILES * (NTILES + 1) / 2)  // 528 upper-tri tiles per pose

#define FK_T   512                           // 8 waves
#define FK_CH  (A_ATOMS / FK_T)              // 8 atoms per thread
#define FK_W   (FK_T / 64)                   // 8 waves

typedef float v2f __attribute__((ext_vector_type(2)));

__device__ __constant__ float c_SIGMA2  = 1.9f * 1.9f;
__device__ __constant__ float c_4EPS    = 0.8f;   // 4 * 0.2
__device__ __constant__ float c_R2SOFT  = 0.25f;

// ---------------- rigid transform (3x4 row-major: r|t) ----------------
struct RT { float m[12]; };

__device__ inline RT rt_identity() {
    RT v;
    v.m[0]=1.f; v.m[1]=0.f; v.m[2]=0.f;  v.m[3]=0.f;
    v.m[4]=0.f; v.m[5]=1.f; v.m[6]=0.f;  v.m[7]=0.f;
    v.m[8]=0.f; v.m[9]=0.f; v.m[10]=1.f; v.m[11]=0.f;
    return v;
}

// C = A o B  (left-to-right chain product: cum = cum @ ht)
__device__ inline RT rt_compose(const RT& a, const RT& b) {
    RT c;
#pragma unroll
    for (int i = 0; i < 3; ++i) {
        float a0 = a.m[i*4+0], a1 = a.m[i*4+1], a2 = a.m[i*4+2];
        c.m[i*4+0] = fmaf(a0, b.m[0], fmaf(a1, b.m[4],  a2*b.m[8]));
        c.m[i*4+1] = fmaf(a0, b.m[1], fmaf(a1, b.m[5],  a2*b.m[9]));
        c.m[i*4+2] = fmaf(a0, b.m[2], fmaf(a1, b.m[6],  a2*b.m[10]));
        c.m[i*4+3] = fmaf(a0, b.m[3], fmaf(a1, b.m[7],  fmaf(a2, b.m[11], a.m[i*4+3])));
    }
    return c;
}

// Accurate trig kept on purpose: the 4096-long compose chain amplifies per-HT
// error; absmax margin vs threshold is only ~2.2x (65536 vs 144179).
__device__ inline RT local_ht(const float* __restrict__ dof) {
    float phi = dof[0], th = dof[1];
    float d = fmaf(0.25f, tanhf(dof[2]), 1.5f);
    float sp, cp, st, ct;
    sincosf(phi, &sp, &cp);
    sincosf(th,  &st, &ct);
    RT h;
    h.m[0] = cp*ct; h.m[1] = -sp; h.m[2]  = cp*st; h.m[3]  = d*cp*ct;
    h.m[4] = sp*ct; h.m[5] =  cp; h.m[6]  = sp*st; h.m[7]  = d*sp*ct;
    h.m[8] = -st;   h.m[9] = 0.f; h.m[10] = ct;    h.m[11] = -d*st;
    return h;
}

// ---------------- kernel 1: forward kinematics + scatter + out zero ----------------
// Hierarchical prefix-compose:
//   phase 1: per-thread chunk product (8 atoms, registers)
//   phase 2: wave-level inclusive shuffle scan (6 steps, no barriers, no LDS)
//   phase 3: one barrier; each wave composes the <=7 preceding wave totals
//            (broadcast LDS reads -- conflict-free)
//   phase 4: per-thread exclusive prefix, replay chunk from registers, scatter
__global__ __launch_bounds__(FK_T) void fk_kernel(const float* __restrict__ dofs,
                                                  const int* __restrict__ kid,
                                                  float* __restrict__ X,
                                                  float* __restrict__ Y,
                                                  float* __restrict__ Z,
                                                  float* __restrict__ out) {
    const int pose = blockIdx.x;
    const int tid  = threadIdx.x;
    const int lane = tid & 63;
    const int wid  = tid >> 6;
    if (tid == 0) out[pose] = 0.f;

    const int a0 = tid * FK_CH;
    const float* dbase = dofs + (size_t)pose * A_ATOMS * 9;

    // phase 1: local HTs in registers (only 4 blocks -> VGPR pressure irrelevant)
    RT h[FK_CH];
#pragma unroll
    for (int k = 0; k < FK_CH; ++k) h[k] = local_ht(dbase + (size_t)(a0 + k) * 9);

    RT M = h[0];
#pragma unroll
    for (int k = 1; k < FK_CH; ++k) M = rt_compose(M, h[k]);

    // phase 2: wave-level inclusive scan (earlier lane on the left)
#pragma unroll
    for (int off = 1; off < 64; off <<= 1) {
        RT l;
#pragma unroll
        for (int i = 0; i < 12; ++i) l.m[i] = __shfl_up(M.m[i], (unsigned)off, 64);
        RT c = rt_compose(l, M);
        bool act = (lane >= off);
#pragma unroll
        for (int i = 0; i < 12; ++i) M.m[i] = act ? c.m[i] : M.m[i];
    }

    // phase 3: cross-wave totals (one barrier)
    __shared__ float wtot[FK_W][12];
    if (lane == 63) {
#pragma unroll
        for (int i = 0; i < 12; ++i) wtot[wid][i] = M.m[i];
    }
    __syncthreads();

    RT P = rt_identity();
    for (int w = 0; w < wid; ++w) {          // wave-uniform trip count
        RT t;
#pragma unroll
        for (int i = 0; i < 12; ++i) t.m[i] = wtot[w][i];  // broadcast read
        P = rt_compose(P, t);
    }

    // phase 4: exclusive per-thread prefix
    RT pm;
#pragma unroll
    for (int i = 0; i < 12; ++i) pm.m[i] = __shfl_up(M.m[i], 1u, 64);
    RT cur;
    if (lane == 0) cur = P;
    else           cur = rt_compose(P, pm);

#pragma unroll
    for (int k = 0; k < FK_CH; ++k) {
        cur = rt_compose(cur, h[k]);
        int g   = pose * A_ATOMS + a0 + k;
        int dst = kid[g];
        X[dst] = cur.m[3];
        Y[dst] = cur.m[7];
        Z[dst] = cur.m[11];
    }
}

// ---------------- kernel 2: pairwise LJ over upper-triangular tiles ----------------
__global__ __launch_bounds__(256) void lj_kernel(const float* __restrict__ X,
                                                 const float* __restrict__ Y,
                                                 const float* __restrict__ Z,
                                                 float* __restrict__ out) {
    const int pose = blockIdx.y;
    // map blockIdx.x -> (bi, bj) with bi <= bj
    int rr = blockIdx.x, bi = 0;
    while (rr >= NTILES - bi) { rr -= NTILES - bi; ++bi; }
    const int bj = bi + rr;

    __shared__ float sxi[TILE], syi[TILE], szi[TILE];
    __shared__ float sxj[TILE], syj[TILE], szj[TILE];

    const int tid = threadIdx.x;
    const float* Xp = X + pose * A_ATOMS;
    const float* Yp = Y + pose * A_ATOMS;
    const float* Zp = Z + pose * A_ATOMS;

    if (tid < TILE) {
        int gi = bi * TILE + tid;
        sxi[tid] = Xp[gi]; syi[tid] = Yp[gi]; szi[tid] = Zp[gi];
    } else {
        int t = tid - TILE;
        int gj = bj * TILE + t;
        sxj[t] = Xp[gj]; syj[t] = Yp[gj]; szj[t] = Zp[gj];
    }
    __syncthreads();

    // 16 i-groups x 16 j-groups; each thread: 8 i-rows x 8 j-cols in registers
    const int i0 = (tid & 15) * 8;
    const int j0 = (tid >> 4) * 8;

    const float SIG2 = c_SIGMA2, SOFT = c_R2SOFT;
    float acc = 0.f;

    if (bi != bj) {
        // off-diagonal tile (496/528): packed fp32 pairs -> v_pk_fma_f32 candidates
        float xi[8], yi[8], zi[8];
#pragma unroll
        for (int k = 0; k < 8; ++k) {
            xi[k] = sxi[i0 + k]; yi[k] = syi[i0 + k]; zi[k] = szi[i0 + k];
        }
        v2f xj2[4], yj2[4], zj2[4];
#pragma unroll
        for (int p = 0; p < 4; ++p) {
            xj2[p] = (v2f){sxj[j0 + 2*p], sxj[j0 + 2*p + 1]};
            yj2[p] = (v2f){syj[j0 + 2*p], syj[j0 + 2*p + 1]};
            zj2[p] = (v2f){szj[j0 + 2*p], szj[j0 + 2*p + 1]};
        }
        const v2f soft2 = (v2f){SOFT, SOFT};
        v2f acc2 = (v2f){0.f, 0.f};
#pragma unroll
        for (int p = 0; p < 4; ++p) {
#pragma unroll
            for (int k = 0; k < 8; ++k) {
                v2f dx = xi[k] - xj2[p];
                v2f dy = yi[k] - yj2[p];
                v2f dz = zi[k] - zj2[p];
                v2f r2 = __builtin_elementwise_fma(dx, dx,
                         __builtin_elementwise_fma(dy, dy,
                         __builtin_elementwise_fma(dz, dz, soft2)));
                v2f rc = (v2f){__builtin_amdgcn_rcpf(r2.x), __builtin_amdgcn_rcpf(r2.y)};
                v2f t  = SIG2 * rc;
                v2f i6 = t * t * t;
                acc2 += __builtin_elementwise_fma(i6, i6, -i6);   // inv12 - inv6
            }
        }
        acc = acc2.x + acc2.y;
    } else {
        // diagonal tile: keep only i < j (scalar masked path)
        float xi[8], yi[8], zi[8], xj[8], yj[8], zj[8];
#pragma unroll
        for (int k = 0; k < 8; ++k) {
            xi[k] = sxi[i0 + k]; yi[k] = syi[i0 + k]; zi[k] = szi[i0 + k];
            xj[k] = sxj[j0 + k]; yj[k] = syj[j0 + k]; zj[k] = szj[j0 + k];
        }
#pragma unroll
        for (int jj = 0; jj < 8; ++jj) {
            int j = j0 + jj;
#pragma unroll
            for (int k = 0; k < 8; ++k) {
                float dx = xi[k] - xj[jj], dy = yi[k] - yj[jj], dz = zi[k] - zj[jj];
                float r2 = fmaf(dx, dx, fmaf(dy, dy, fmaf(dz, dz, SOFT)));
                float t  = SIG2 * __builtin_amdgcn_rcpf(r2);
                float i6 = t * t * t;
                float hh = fmaf(i6, i6, -i6);
                acc += ((i0 + k) < j) ? hh : 0.f;
            }
        }
    }
    acc *= c_4EPS;

    // wave64 reduce then cross-wave via LDS
#pragma unroll
    for (int off = 32; off > 0; off >>= 1) acc += __shfl_down(acc, off, 64);

    __shared__ float wsum[4];
    int lane = tid & 63, wid = tid >> 6;
    if (lane == 0) wsum[wid] = acc;
    __syncthreads();
    if (tid == 0) {
        float s = wsum[0] + wsum[1] + wsum[2] + wsum[3];
        atomicAdd(out + pose, s);
    }
}

// ---------------- launch ----------------
extern "C" void kernel_launch(void* const* d_in, const int* in_sizes, int n_in,
                              void* d_out, int out_size, void* d_ws, size_t ws_size,
                              hipStream_t stream) {
    (void)in_sizes; (void)n_in; (void)out_size; (void)ws_size;
    const float* dofs = (const float*)d_in[0];
    const int*   kid  = (const int*)d_in[2];
    float*       out  = (float*)d_out;

    float* X = (float*)d_ws;       // N_TOT floats
    float* Y = X + N_TOT;
    float* Z = Y + N_TOT;

    fk_kernel<<<P_POSES, FK_T, 0, stream>>>(dofs, kid, X, Y, Z, out);
    dim3 grid(NPAIRT, P_POSES);
    lj_kernel<<<grid, 256, 0, stream>>>(X, Y, Z, out);
}